// Round 1
// 806.747 us; speedup vs baseline: 1.2589x; 1.2589x over previous
//
#include <hip/hip_runtime.h>
#include <math.h>

typedef unsigned short u16;
typedef unsigned int u32;
typedef __bf16 bf16x8 __attribute__((ext_vector_type(8)));
typedef float f32x4 __attribute__((ext_vector_type(4)));

__device__ __forceinline__ float b2f(u16 u) { return __uint_as_float(((u32)u) << 16); }
__device__ __forceinline__ u16 f2b(float f) {
    u32 x = __float_as_uint(f);
    return (u16)((x + 0x7FFFu + ((x >> 16) & 1u)) >> 16);
}
__device__ __forceinline__ void load8f(const float* p, size_t idx, float* o) {
    const float4* q = (const float4*)(p + idx);
    float4 a = q[0], b = q[1];
    o[0]=a.x; o[1]=a.y; o[2]=a.z; o[3]=a.w; o[4]=b.x; o[5]=b.y; o[6]=b.z; o[7]=b.w;
}
// async global->LDS, 16B per lane; LDS dest = wave-uniform base + lane*16
__device__ __forceinline__ void gld16(const void* g, void* l) {
    __builtin_amdgcn_global_load_lds(
        (const __attribute__((address_space(1))) u32*)g,
        (__attribute__((address_space(3))) u32*)l, 16, 0, 0);
}

// ---------------- weight transpose+convert: Wt[n][k] = bf16(W[k][n] * scale) ----------------
__global__ __launch_bounds__(256) void transpose_k(const float* __restrict__ Win, u16* __restrict__ Wt,
                                                   int Kd, int Nd, float scale) {
    __shared__ u16 tile[32][33];
    int tx = threadIdx.x & 31, ty = threadIdx.x >> 5;
    int k0 = blockIdx.x << 5, n0 = blockIdx.y << 5;
#pragma unroll
    for (int r = 0; r < 4; r++)
        tile[ty + 8 * r][tx] = f2b(Win[(size_t)(k0 + ty + 8 * r) * Nd + (n0 + tx)] * scale);
    __syncthreads();
#pragma unroll
    for (int r = 0; r < 4; r++)
        Wt[(size_t)(n0 + ty + 8 * r) * Kd + (k0 + tx)] = tile[tx][ty + 8 * r];
}

// ---------------- LN1 (stats fused) + shift + window partition: token-order iteration ----------------
__global__ __launch_bounds__(256) void ln1win_k(const float* __restrict__ x, const float* __restrict__ g,
                                                const float* __restrict__ bta, u16* __restrict__ win) {
    int wave = threadIdx.x >> 6, lane = threadIdx.x & 63;
    int token = blockIdx.x * 4 + wave;                  // token-order row
    int b = token / 4800, rem = token - b * 4800;
    int h = rem / 60, w = rem - h * 60;
    int hr = h + 75; if (hr >= 80) hr -= 80;            // (h-5) mod 80 : rolled coord
    int wr = w + 55; if (wr >= 60) wr -= 60;
    int widx = (hr / 10) * 6 + (wr / 10);
    int l = (hr - (hr / 10) * 10) * 10 + (wr - (wr / 10) * 10);
    size_t dstrow = ((size_t)b * 48 + widx) * 100 + l;  // window-order row
    int c0 = lane * 8;
    float v[8]; load8f(x, (size_t)token * 512 + c0, v);
    float s = 0.f, s2 = 0.f;
#pragma unroll
    for (int e = 0; e < 8; e++) { s += v[e]; s2 += v[e] * v[e]; }
#pragma unroll
    for (int o = 32; o > 0; o >>= 1) { s += __shfl_xor(s, o); s2 += __shfl_xor(s2, o); }
    float mean = s * (1.0f / 512.0f);
    float var = fmaxf(s2 * (1.0f / 512.0f) - mean * mean, 0.0f);
    float rstd = rsqrtf(var + 1e-5f);
    uint4 o4; u16* ou = (u16*)&o4;
#pragma unroll
    for (int e = 0; e < 8; e++)
        ou[e] = f2b((v[e] - mean) * rstd * g[c0 + e] + bta[c0 + e]);
    *(uint4*)(win + dstrow * 512 + c0) = o4;
}

// ---------------- window reverse + residual + fused LN2: hs, ln2y ----------------
__global__ __launch_bounds__(256) void resid2_k(const float* __restrict__ shortcut, const u16* __restrict__ attn_out,
                                                const float* __restrict__ g, const float* __restrict__ bta,
                                                u16* __restrict__ hs, u16* __restrict__ ln2y) {
    int wave = threadIdx.x >> 6, lane = threadIdx.x & 63;
    int token = blockIdx.x * 4 + wave;
    int b = token / 4800, rem = token - b * 4800;
    int h = rem / 60, w = rem - h * 60;
    int hr = h + 75; if (hr >= 80) hr -= 80;
    int wr = w + 55; if (wr >= 60) wr -= 60;
    int widx = (hr / 10) * 6 + (wr / 10);
    int l = (hr - (hr / 10) * 10) * 10 + (wr - (wr / 10) * 10);
    size_t arow = ((size_t)b * 48 + widx) * 100 + l;
    int c0 = lane * 8;
    float sv[8]; load8f(shortcut, (size_t)token * 512 + c0, sv);
    uint4 da = *(const uint4*)(attn_out + arow * 512 + c0);
    const u16* au = (const u16*)&da;
    float hv[8]; float s = 0.f, s2 = 0.f;
    uint4 oh; u16* ohu = (u16*)&oh;
#pragma unroll
    for (int e = 0; e < 8; e++) {
        hv[e] = sv[e] + b2f(au[e]);
        s += hv[e]; s2 += hv[e] * hv[e];
        ohu[e] = f2b(hv[e]);
    }
    *(uint4*)(hs + (size_t)token * 512 + c0) = oh;
#pragma unroll
    for (int off = 32; off > 0; off >>= 1) { s += __shfl_xor(s, off); s2 += __shfl_xor(s2, off); }
    float mean = s * (1.0f / 512.0f);
    float var = fmaxf(s2 * (1.0f / 512.0f) - mean * mean, 0.0f);
    float rstd = rsqrtf(var + 1e-5f);
    uint4 oy; u16* oyu = (u16*)&oy;
#pragma unroll
    for (int e = 0; e < 8; e++)
        oyu[e] = f2b((hv[e] - mean) * rstd * g[c0 + e] + bta[c0 + e]);
    *(uint4*)(ln2y + (size_t)token * 512 + c0) = oy;
}

// ---------------- MFMA GEMM (m97-style): C = epi(A[M,K] @ Bt[N,K]^T + bias*bscale) ----------------
// EPI: 0 = bias; 1 = bias + tanh-GELU; 2 = bias + residual add (res bf16 [M,512])
// OF32: output fp32 instead of bf16
template <int EPI, int OF32>
__global__ __launch_bounds__(256) void gemm_k(const u16* __restrict__ A, const u16* __restrict__ Bt,
                                              const float* __restrict__ bias, const u16* __restrict__ res,
                                              void* __restrict__ C, float bscale, int M, int N, int K) {
    __shared__ __align__(16) u16 As[128 * 32];   // unpadded: required by global_load_lds lane mapping
    __shared__ __align__(16) u16 Bs[128 * 32];
    int tid = threadIdx.x;
    int wave = tid >> 6, lane = tid & 63;
    int l15 = lane & 15, quad = lane >> 4;
    int lq = lane >> 2, lr = lane & 3;           // 16 rows x 4 16B-chunks per wave round
    int wm = (wave >> 1) * 64, wn = (wave & 1) * 64;
    int bm = blockIdx.x, bn = blockIdx.y;

    f32x4 acc[4][4];
#pragma unroll
    for (int i = 0; i < 4; i++)
#pragma unroll
        for (int j = 0; j < 4; j++) acc[i][j] = (f32x4){0.f, 0.f, 0.f, 0.f};

    const u16* Ab = A + (size_t)(bm * 128) * K;
    const u16* Bb = Bt + (size_t)(bn * 128) * K;

    for (int kt = 0; kt < K; kt += 32) {
#pragma unroll
        for (int h = 0; h < 2; h++) {
            int r = h * 64 + wave * 16 + lq;
            gld16(Ab + (size_t)r * K + kt + lr * 8, &As[(h * 64 + wave * 16) * 32]);
            gld16(Bb + (size_t)r * K + kt + lr * 8, &Bs[(h * 64 + wave * 16) * 32]);
        }
        __syncthreads();
        bf16x8 af[4], bfr[4];
#pragma unroll
        for (int t = 0; t < 4; t++) {
            af[t]  = *(const bf16x8*)(&As[(wm + t * 16 + l15) * 32 + quad * 8]);
            bfr[t] = *(const bf16x8*)(&Bs[(wn + t * 16 + l15) * 32 + quad * 8]);
        }
#pragma unroll
        for (int i = 0; i < 4; i++)
#pragma unroll
            for (int j = 0; j < 4; j++)
                acc[i][j] = __builtin_amdgcn_mfma_f32_16x16x32_bf16(af[i], bfr[j], acc[i][j], 0, 0, 0);
        __syncthreads();
    }

    // C/D layout: col = lane&15, row = quad*4 + reg
#pragma unroll
    for (int i = 0; i < 4; i++) {
        int row0 = bm * 128 + wm + i * 16 + quad * 4;
#pragma unroll
        for (int j = 0; j < 4; j++) {
            int col = bn * 128 + wn + j * 16 + l15;
            float bv = bias[col] * bscale;
#pragma unroll
            for (int rr = 0; rr < 4; rr++) {
                int row = row0 + rr;
                float v = acc[i][j][rr] + bv;
                if (EPI == 1) {   // tanh-form GELU: |err| < 1e-3, tolerance 0.115
                    float zz = 1.5957691216f * (v + 0.044715f * v * v * v);  // 2*0.7978845608
                    float t = 1.0f - 2.0f / (__expf(zz) + 1.0f);             // tanh(zz/... )
                    v = 0.5f * v * (1.0f + t);
                }
                if (EPI == 2) v += b2f(res[(size_t)row * 512 + col]);
                if (OF32) ((float*)C)[(size_t)row * N + col] = v;
                else      ((u16*)C)[(size_t)row * N + col] = f2b(v);
            }
        }
    }
}

// ---------------- bias precompute: biasM[wtype][head][q][kpad=112] = rel_bias + mask, -1e30 pad ----------------
// wtype: bit1 = bottom-edge window (wh==7), bit0 = right-edge (ww==5). 4*16*100*112 = 716800 elems.
__global__ __launch_bounds__(256) void biasprep_k(const float* __restrict__ table, u16* __restrict__ biasM) {
    int idx = blockIdx.x * 256 + threadIdx.x;
    int k = idx % 112;
    int t = idx / 112;
    int q = t % 100; t /= 100;
    int head = t & 15, wt = t >> 4;
    float v;
    if (k >= 100) {
        v = -1e30f;
    } else {
        int qi = q / 10, qj = q - qi * 10;
        int ki = k / 10, kj = k - ki * 10;
        int rel = (qi - ki) * 19 + (qj - kj) + 180;   // = qoff - koff + 180
        v = table[rel * 16 + head];
        int rq = ((wt & 2) ? (qi < 5 ? 4 : 8) : 0) + ((wt & 1) ? (qj < 5 ? 1 : 2) : 0);
        int rk = ((wt & 2) ? (ki < 5 ? 4 : 8) : 0) + ((wt & 1) ? (kj < 5 ? 1 : 2) : 0);
        if (rq != rk) v -= 100.0f;
    }
    biasM[idx] = f2b(v);
}

// ---------------- MFMA windowed attention: one WAVE per (window, head) ----------------
// Swapped orientation: S^T[k][q] = K·(s·Q)^T + biasM  (scale folded into wq/bq upstream).
// C/D layout (16x16x32): col = lane&15, row = quad*4 + reg.
//   QK^T: A = K rows (k), B = Q rows (q)  ->  lane holds k = i*16+quad*4+rr for column q = j*16+l15.
//   Softmax over k = per-lane 28 values + shfl_xor(16,32) across quads.
//   PV:   out^T[d][q]: A = V^T rows (d) from swizzled LDS, B = P rows (q) from swizzled LDS.
// Per-wave LDS: Vt[32][128] (8KB) + P[16][128] (4KB), XOR-swizzled (u16 idx: k ^ ((row&7)<<3)).
// No __syncthreads anywhere (all LDS wave-private).
__global__ __launch_bounds__(256, 3) void attn_mfma_k(const u16* __restrict__ Q, const u16* __restrict__ Km,
                                                      const u16* __restrict__ V, const u16* __restrict__ biasM,
                                                      u16* __restrict__ ctx) {
    __shared__ __align__(16) u16 lds[4 * 6144];   // 48KB: 4 waves x (Vt 4096 + P 2048) u16
    int tid = threadIdx.x;
    int wave = tid >> 6, lane = tid & 63;
    int l15 = lane & 15, quad = lane >> 4;
    int bid = blockIdx.x;                 // 1536 blocks = 384 windows x 4
    int win = bid >> 2;
    int head = ((bid & 3) << 2) + wave;   // 4 waves cover 4 heads
    int w48 = win % 48;
    int wh = w48 / 6, ww = w48 - wh * 6;
    int wtype = ((wh == 7) ? 2 : 0) + ((ww == 5) ? 1 : 0);
    size_t base = (size_t)win * 51200 + head * 32;
    u16* Vt = lds + wave * 6144;          // [32 d][128 k] swizzled
    u16* Pl = Vt + 4096;                  // [16 q][128 k] swizzled
    const u16* bptr = biasM + (size_t)(wtype * 16 + head) * 11200;

    // zero Vt logical k in [96,128) (garbage * P=0 would be NaN otherwise)
    {
        uint4 z = {0u, 0u, 0u, 0u};
#pragma unroll
        for (int r = 0; r < 2; r++) {
            int c = r * 64 + lane;        // 0..127 = 32 d-rows x 4 8-wide segs
            int d = c >> 2, seg = c & 3;
            int k0 = 96 + seg * 8;
            *(uint4*)(Vt + d * 128 + (k0 ^ ((d & 7) << 3))) = z;
        }
        uint2 z2 = {0u, 0u};              // zero P logical k in [112,128)
        *(uint2*)(Pl + l15 * 128 + ((112 + quad * 4) ^ ((l15 & 7) << 3))) = z2;
    }
    // stage V transposed: Vt[d][k] = V[k][d]
#pragma unroll
    for (int r = 0; r < 2; r++) {
        int k = r * 64 + lane;
        if (k < 100) {
            const uint4* vp = (const uint4*)(V + base + (size_t)k * 512);
#pragma unroll
            for (int c = 0; c < 4; c++) {
                uint4 dv = vp[c];
                const u16* e = (const u16*)&dv;
#pragma unroll
                for (int t = 0; t < 8; t++) {
                    int d = c * 8 + t;
                    Vt[d * 128 + (k ^ ((d & 7) << 3))] = e[t];
                }
            }
        }
    }
    // K A-frags (resident): lane l15 = key row, quad*8 = d chunk; rows >=100 clamped (masked by bias)
    bf16x8 kf[7];
#pragma unroll
    for (int i = 0; i < 7; i++) {
        int kr = i * 16 + l15; if (kr > 99) kr = 99;
        kf[i] = *(const bf16x8*)(Km + base + (size_t)kr * 512 + quad * 8);
    }
    // V^T A-frags (resident): lane l15 = d row
    bf16x8 vf[2][4];
#pragma unroll
    for (int it = 0; it < 2; it++)
#pragma unroll
        for (int ks = 0; ks < 4; ks++) {
            int D = it * 16 + l15;
            vf[it][ks] = *(const bf16x8*)(Vt + D * 128 + ((ks * 32 + quad * 8) ^ ((D & 7) << 3)));
        }

#pragma unroll 1
    for (int j = 0; j < 7; j++) {
        int q = j * 16 + l15;
        int qc = q > 99 ? 99 : q;         // duplicated q columns never stored
        bf16x8 qf = *(const bf16x8*)(Q + base + (size_t)qc * 512 + quad * 8);
        // C-init from precomputed bias+mask (bf16, 4 consecutive k per lane)
        f32x4 s[7];
#pragma unroll
        for (int i = 0; i < 7; i++) {
            uint2 bb = *(const uint2*)(bptr + (size_t)qc * 112 + i * 16 + quad * 4);
            const u16* be = (const u16*)&bb;
            s[i][0] = b2f(be[0]); s[i][1] = b2f(be[1]);
            s[i][2] = b2f(be[2]); s[i][3] = b2f(be[3]);
        }
#pragma unroll
        for (int i = 0; i < 7; i++)
            s[i] = __builtin_amdgcn_mfma_f32_16x16x32_bf16(kf[i], qf, s[i], 0, 0, 0);
        // softmax over k for column q (28 per-lane values + cross-quad combine)
        float m = -1e30f;
#pragma unroll
        for (int i = 0; i < 7; i++)
#pragma unroll
            for (int rr = 0; rr < 4; rr++) m = fmaxf(m, s[i][rr]);
        m = fmaxf(m, __shfl_xor(m, 16));
        m = fmaxf(m, __shfl_xor(m, 32));
        float l = 0.f;
#pragma unroll
        for (int i = 0; i < 7; i++)
#pragma unroll
            for (int rr = 0; rr < 4; rr++) { s[i][rr] = __expf(s[i][rr] - m); l += s[i][rr]; }
        l += __shfl_xor(l, 16);
        l += __shfl_xor(l, 32);
        // P -> bf16 -> swizzled LDS (row = q-within-16 = l15)
#pragma unroll
        for (int i = 0; i < 7; i++) {
            u32 lo, hi;
            asm("v_cvt_pk_bf16_f32 %0, %1, %2" : "=v"(lo) : "v"(s[i][0]), "v"(s[i][1]));
            asm("v_cvt_pk_bf16_f32 %0, %1, %2" : "=v"(hi) : "v"(s[i][2]), "v"(s[i][3]));
            uint2 w; w.x = lo; w.y = hi;
            *(uint2*)(Pl + l15 * 128 + ((i * 16 + quad * 4) ^ ((l15 & 7) << 3))) = w;
        }
        // PV: out^T[d][q] accumulated over 4 k-steps of 32
        f32x4 o0 = (f32x4){0.f, 0.f, 0.f, 0.f};
        f32x4 o1 = (f32x4){0.f, 0.f, 0.f, 0.f};
#pragma unroll
        for (int ks = 0; ks < 4; ks++) {
            bf16x8 pf = *(const bf16x8*)(Pl + l15 * 128 + ((ks * 32 + quad * 8) ^ ((l15 & 7) << 3)));
            o0 = __builtin_amdgcn_mfma_f32_16x16x32_bf16(vf[0][ks], pf, o0, 0, 0, 0);
            o1 = __builtin_amdgcn_mfma_f32_16x16x32_bf16(vf[1][ks], pf, o1, 0, 0, 0);
        }
        float inv = 1.0f / l;
        if (q < 100) {
            u16* cp = ctx + base + (size_t)q * 512;
            {
                float a0 = o0[0]*inv, a1 = o0[1]*inv, a2 = o0[2]*inv, a3 = o0[3]*inv;
                u32 lo, hi;
                asm("v_cvt_pk_bf16_f32 %0, %1, %2" : "=v"(lo) : "v"(a0), "v"(a1));
                asm("v_cvt_pk_bf16_f32 %0, %1, %2" : "=v"(hi) : "v"(a2), "v"(a3));
                uint2 w; w.x = lo; w.y = hi;
                *(uint2*)(cp + quad * 4) = w;
            }
            {
                float a0 = o1[0]*inv, a1 = o1[1]*inv, a2 = o1[2]*inv, a3 = o1[3]*inv;
                u32 lo, hi;
                asm("v_cvt_pk_bf16_f32 %0, %1, %2" : "=v"(lo) : "v"(a0), "v"(a1));
                asm("v_cvt_pk_bf16_f32 %0, %1, %2" : "=v"(hi) : "v"(a2), "v"(a3));
                uint2 w; w.x = lo; w.y = hi;
                *(uint2*)(cp + 16 + quad * 4) = w;
            }
        }
    }
}

extern "C" void kernel_launch(void* const* d_in, const int* in_sizes, int n_in,
                              void* d_out, int out_size, void* d_ws, size_t ws_size,
                              hipStream_t stream) {
    const float* hidden = (const float*)d_in[0];
    const float* ln1_g  = (const float*)d_in[1];
    const float* ln1_b  = (const float*)d_in[2];
    const float* wq = (const float*)d_in[3];  const float* bq = (const float*)d_in[4];
    const float* wk = (const float*)d_in[5];  const float* bk = (const float*)d_in[6];
    const float* wv = (const float*)d_in[7];  const float* bv = (const float*)d_in[8];
    const float* wo = (const float*)d_in[9];  const float* bo = (const float*)d_in[10];
    const float* rel = (const float*)d_in[11];
    const float* ln2_g = (const float*)d_in[12];
    const float* ln2_b = (const float*)d_in[13];
    const float* w1 = (const float*)d_in[14]; const float* b1 = (const float*)d_in[15];
    const float* w2 = (const float*)d_in[16]; const float* b2 = (const float*)d_in[17];

    // ws: R0,R1,Rh = 3*NTC bf16 (118MB) + weights. d_out doubles as V / ln2y park.
    //   R0: win -> ctx -> h1 chunk ; R1: q -> attn_out ; Rh: k -> hs
    //   d_out lo-half (bf16): v -> ln2y ; biasM parked at d_out+NTC u16 (1.4MB, free until
    //   FFN chunk mc=2 fp32 writes land there — attn is long done by then).
    const size_t NTC = 38400ull * 512;
    u16* ws = (u16*)d_ws;
    u16* R0 = ws;
    u16* R1 = ws + NTC;
    u16* Rh = ws + 2 * NTC;
    u16* wqt = ws + 3 * NTC;
    u16* wkt = wqt + 512 * 512;
    u16* wvt = wkt + 512 * 512;
    u16* wot = wvt + 512 * 512;
    u16* w1t = wot + 512 * 512;      // (2048,512)
    u16* w2t = w1t + 1048576;        // (512,2048)
    u16* dlo = (u16*)d_out;          // v, then ln2y (bf16)
    u16* biasM = dlo + NTC;          // [4][16][100][112] bf16
    float* outp = (float*)d_out;

    const float SC = 0.17677669529663689f;   // 1/sqrt(32), folded into wq/bq

    transpose_k<<<dim3(16, 16), 256, 0, stream>>>(wq, wqt, 512, 512, SC);
    transpose_k<<<dim3(16, 16), 256, 0, stream>>>(wk, wkt, 512, 512, 1.0f);
    transpose_k<<<dim3(16, 16), 256, 0, stream>>>(wv, wvt, 512, 512, 1.0f);
    transpose_k<<<dim3(16, 16), 256, 0, stream>>>(wo, wot, 512, 512, 1.0f);
    transpose_k<<<dim3(16, 64), 256, 0, stream>>>(w1, w1t, 512, 2048, 1.0f);
    transpose_k<<<dim3(64, 16), 256, 0, stream>>>(w2, w2t, 2048, 512, 1.0f);

    biasprep_k<<<2800, 256, 0, stream>>>(rel, biasM);   // 716800 = 2800*256 exactly

    ln1win_k<<<9600, 256, 0, stream>>>(hidden, ln1_g, ln1_b, R0 /*win*/);

    gemm_k<0, 0><<<dim3(300, 4), 256, 0, stream>>>(R0, wqt, bq, nullptr, R1 /*q*/, SC, 38400, 512, 512);
    gemm_k<0, 0><<<dim3(300, 4), 256, 0, stream>>>(R0, wkt, bk, nullptr, Rh /*k*/, 1.0f, 38400, 512, 512);
    gemm_k<0, 0><<<dim3(300, 4), 256, 0, stream>>>(R0, wvt, bv, nullptr, dlo /*v*/, 1.0f, 38400, 512, 512);

    attn_mfma_k<<<1536, 256, 0, stream>>>(R1, Rh, dlo, biasM, R0 /*ctx*/);

    gemm_k<0, 0><<<dim3(300, 4), 256, 0, stream>>>(R0, wot, bo, nullptr, R1 /*attn_out*/, 1.0f, 38400, 512, 512);

    resid2_k<<<9600, 256, 0, stream>>>(hidden, R1, ln2_g, ln2_b, Rh /*hs*/, dlo /*ln2y*/);

    // FFN chunks in REVERSE order so fp32 out writes never clobber unread bf16 ln2y rows:
    // chunk mc reads ln2y bf16 bytes [mc*9.83MB, +9.83MB); writes fp32 [mc*19.66MB, +19.66MB).
    for (int mc = 3; mc >= 0; mc--) {
        size_t roff = (size_t)mc * 9600 * 512;
        gemm_k<1, 0><<<dim3(75, 16), 256, 0, stream>>>(dlo + roff, w1t, b1, nullptr, R0 /*h1*/,
                                                       1.0f, 9600, 2048, 512);
        gemm_k<2, 1><<<dim3(75, 4), 256, 0, stream>>>(R0, w2t, b2, Rh + roff, outp + roff,
                                                      1.0f, 9600, 512, 2048);
    }
}

// Round 2
// 749.830 us; speedup vs baseline: 1.3544x; 1.0759x over previous
//
#include <hip/hip_runtime.h>
#include <math.h>

typedef unsigned short u16;
typedef unsigned int u32;
typedef __bf16 bf16x8 __attribute__((ext_vector_type(8)));
typedef float f32x4 __attribute__((ext_vector_type(4)));

__device__ __forceinline__ float b2f(u16 u) { return __uint_as_float(((u32)u) << 16); }
__device__ __forceinline__ u16 f2b(float f) {
    u32 x = __float_as_uint(f);
    return (u16)((x + 0x7FFFu + ((x >> 16) & 1u)) >> 16);
}
__device__ __forceinline__ void load8f(const float* p, size_t idx, float* o) {
    const float4* q = (const float4*)(p + idx);
    float4 a = q[0], b = q[1];
    o[0]=a.x; o[1]=a.y; o[2]=a.z; o[3]=a.w; o[4]=b.x; o[5]=b.y; o[6]=b.z; o[7]=b.w;
}
// async global->LDS, 16B per lane; LDS dest = wave-uniform base + lane*16
__device__ __forceinline__ void gld16(const void* g, void* l) {
    __builtin_amdgcn_global_load_lds(
        (const __attribute__((address_space(1))) u32*)g,
        (__attribute__((address_space(3))) u32*)l, 16, 0, 0);
}

// ---------------- weight transpose+convert: Wt[n][k] = bf16(W[k][n] * scale) ----------------
__global__ __launch_bounds__(256) void transpose_k(const float* __restrict__ Win, u16* __restrict__ Wt,
                                                   int Kd, int Nd, float scale) {
    __shared__ u16 tile[32][33];
    int tx = threadIdx.x & 31, ty = threadIdx.x >> 5;
    int k0 = blockIdx.x << 5, n0 = blockIdx.y << 5;
#pragma unroll
    for (int r = 0; r < 4; r++)
        tile[ty + 8 * r][tx] = f2b(Win[(size_t)(k0 + ty + 8 * r) * Nd + (n0 + tx)] * scale);
    __syncthreads();
#pragma unroll
    for (int r = 0; r < 4; r++)
        Wt[(size_t)(n0 + ty + 8 * r) * Kd + (k0 + tx)] = tile[tx][ty + 8 * r];
}

// ---------------- concat qkv bias (scale folded into q part) ----------------
__global__ __launch_bounds__(256) void biascat_k(const float* __restrict__ bq, const float* __restrict__ bk,
                                                 const float* __restrict__ bv, float* __restrict__ o) {
    int i = blockIdx.x * 256 + threadIdx.x;   // 1536
    float v = (i < 512) ? bq[i] * 0.17677669529663689f : (i < 1024 ? bk[i - 512] : bv[i - 1024]);
    o[i] = v;
}

// ---------------- LN1 (stats fused) + shift + window partition ----------------
__global__ __launch_bounds__(256) void ln1win_k(const float* __restrict__ x, const float* __restrict__ g,
                                                const float* __restrict__ bta, u16* __restrict__ win) {
    int wave = threadIdx.x >> 6, lane = threadIdx.x & 63;
    int token = blockIdx.x * 4 + wave;                  // token-order row
    int b = token / 4800, rem = token - b * 4800;
    int h = rem / 60, w = rem - h * 60;
    int hr = h + 75; if (hr >= 80) hr -= 80;            // (h-5) mod 80 : rolled coord
    int wr = w + 55; if (wr >= 60) wr -= 60;
    int widx = (hr / 10) * 6 + (wr / 10);
    int l = (hr - (hr / 10) * 10) * 10 + (wr - (wr / 10) * 10);
    size_t dstrow = ((size_t)b * 48 + widx) * 100 + l;  // window-order row
    int c0 = lane * 8;
    float v[8]; load8f(x, (size_t)token * 512 + c0, v);
    float s = 0.f, s2 = 0.f;
#pragma unroll
    for (int e = 0; e < 8; e++) { s += v[e]; s2 += v[e] * v[e]; }
#pragma unroll
    for (int o = 32; o > 0; o >>= 1) { s += __shfl_xor(s, o); s2 += __shfl_xor(s2, o); }
    float mean = s * (1.0f / 512.0f);
    float var = fmaxf(s2 * (1.0f / 512.0f) - mean * mean, 0.0f);
    float rstd = rsqrtf(var + 1e-5f);
    uint4 o4; u16* ou = (u16*)&o4;
#pragma unroll
    for (int e = 0; e < 8; e++)
        ou[e] = f2b((v[e] - mean) * rstd * g[c0 + e] + bta[c0 + e]);
    *(uint4*)(win + dstrow * 512 + c0) = o4;
}

// ---------------- window reverse + residual + fused LN2: hs, ln2y ----------------
__global__ __launch_bounds__(256) void resid2_k(const float* __restrict__ shortcut, const u16* __restrict__ attn_out,
                                                const float* __restrict__ g, const float* __restrict__ bta,
                                                u16* __restrict__ hs, u16* __restrict__ ln2y) {
    int wave = threadIdx.x >> 6, lane = threadIdx.x & 63;
    int token = blockIdx.x * 4 + wave;
    int b = token / 4800, rem = token - b * 4800;
    int h = rem / 60, w = rem - h * 60;
    int hr = h + 75; if (hr >= 80) hr -= 80;
    int wr = w + 55; if (wr >= 60) wr -= 60;
    int widx = (hr / 10) * 6 + (wr / 10);
    int l = (hr - (hr / 10) * 10) * 10 + (wr - (wr / 10) * 10);
    size_t arow = ((size_t)b * 48 + widx) * 100 + l;
    int c0 = lane * 8;
    float sv[8]; load8f(shortcut, (size_t)token * 512 + c0, sv);
    uint4 da = *(const uint4*)(attn_out + arow * 512 + c0);
    const u16* au = (const u16*)&da;
    float hv[8]; float s = 0.f, s2 = 0.f;
    uint4 oh; u16* ohu = (u16*)&oh;
#pragma unroll
    for (int e = 0; e < 8; e++) {
        hv[e] = sv[e] + b2f(au[e]);
        s += hv[e]; s2 += hv[e] * hv[e];
        ohu[e] = f2b(hv[e]);
    }
    *(uint4*)(hs + (size_t)token * 512 + c0) = oh;
#pragma unroll
    for (int off = 32; off > 0; off >>= 1) { s += __shfl_xor(s, off); s2 += __shfl_xor(s2, off); }
    float mean = s * (1.0f / 512.0f);
    float var = fmaxf(s2 * (1.0f / 512.0f) - mean * mean, 0.0f);
    float rstd = rsqrtf(var + 1e-5f);
    uint4 oy; u16* oyu = (u16*)&oy;
#pragma unroll
    for (int e = 0; e < 8; e++)
        oyu[e] = f2b((hv[e] - mean) * rstd * g[c0 + e] + bta[c0 + e]);
    *(uint4*)(ln2y + (size_t)token * 512 + c0) = oy;
}

// ---------------- MFMA GEMM, depth-2 counted-vmcnt pipeline ----------------
// C = epi(A[M,K] @ Bt[N,K]^T + bias)
// EPI: 0 = bias; 1 = bias + tanh-GELU; 2 = bias + residual add (res bf16 [M,512])
// OF32: output fp32. QKV: N=512 stride, route output by bn>>2 to C0/C1/C2, bias indexed 0..1535.
// 3 LDS buffers (48KB), prefetch distance 2, s_waitcnt vmcnt(8) steady state (never 0 mid-loop).
template <int EPI, int OF32, int QKV>
__global__ __launch_bounds__(256) void gemm_k(const u16* __restrict__ A, const u16* __restrict__ Bt,
                                              const float* __restrict__ bias, const u16* __restrict__ res,
                                              void* __restrict__ C0, void* __restrict__ C1, void* __restrict__ C2,
                                              int M, int N, int K) {
    __shared__ __align__(16) u16 As[3][128 * 32];   // unpadded: required by global_load_lds lane mapping
    __shared__ __align__(16) u16 Bs[3][128 * 32];
    int tid = threadIdx.x;
    int wave = tid >> 6, lane = tid & 63;
    int l15 = lane & 15, quad = lane >> 4;
    int lq = lane >> 2, lr = lane & 3;           // 16 rows x 4 16B-chunks per wave round
    int wm = (wave >> 1) * 64, wn = (wave & 1) * 64;

    // XCD-aware bijective swizzle (m204), bn-fastest flatten: concurrent same-XCD blocks share A-tile
    int gx = gridDim.x, gy = gridDim.y;
    int nwg = gx * gy;
    int orig = blockIdx.x * gy + blockIdx.y;
    int q8 = nwg >> 3, r8 = nwg & 7;
    int xcd = orig & 7, loc = orig >> 3;
    int wg = (xcd < r8 ? xcd * (q8 + 1) : r8 * (q8 + 1) + (xcd - r8) * q8) + loc;
    int bn = wg % gy, bm = wg / gy;

    f32x4 acc[4][4];
#pragma unroll
    for (int i = 0; i < 4; i++)
#pragma unroll
        for (int j = 0; j < 4; j++) acc[i][j] = (f32x4){0.f, 0.f, 0.f, 0.f};

    const u16* Ab = A + (size_t)(bm * 128) * K;
    const u16* Bb = Bt + (size_t)(bn * 128) * K;

    int T = K >> 5;   // K-steps of 32; K >= 64 always
    auto STAGE = [&](int b, int t) {
        int kt = t << 5;
#pragma unroll
        for (int h = 0; h < 2; h++) {
            int r = h * 64 + wave * 16 + lq;
            gld16(Ab + (size_t)r * K + kt + lr * 8, &As[b][(h * 64 + wave * 16) * 32]);
            gld16(Bb + (size_t)r * K + kt + lr * 8, &Bs[b][(h * 64 + wave * 16) * 32]);
        }
    };

    STAGE(0, 0);
    STAGE(1, 1);
    for (int t = 0; t < T; t++) {
        int cb = t % 3;
        if (t + 2 < T) STAGE((t + 2) % 3, t + 2);
        // wait for tile t only; keep tiles t+1 (and t+2) in flight across the barrier
        if (t + 2 < T)      asm volatile("s_waitcnt vmcnt(8)" ::: "memory");
        else if (t + 1 < T) asm volatile("s_waitcnt vmcnt(4)" ::: "memory");
        else                asm volatile("s_waitcnt vmcnt(0)" ::: "memory");
        __builtin_amdgcn_s_barrier();            // all waves: tile t resident in LDS
        asm volatile("" ::: "memory");
        bf16x8 af[4], bfr[4];
#pragma unroll
        for (int x = 0; x < 4; x++) {
            af[x]  = *(const bf16x8*)(&As[cb][(wm + x * 16 + l15) * 32 + quad * 8]);
            bfr[x] = *(const bf16x8*)(&Bs[cb][(wn + x * 16 + l15) * 32 + quad * 8]);
        }
        asm volatile("s_waitcnt lgkmcnt(0)" ::: "memory");
        __builtin_amdgcn_sched_barrier(0);       // rule #18: pin MFMA after lgkmcnt
        __builtin_amdgcn_s_barrier();            // all waves done reading buf[cb] (next iter overwrites it)
        asm volatile("" ::: "memory");
#pragma unroll
        for (int i = 0; i < 4; i++)
#pragma unroll
            for (int j = 0; j < 4; j++)
                acc[i][j] = __builtin_amdgcn_mfma_f32_16x16x32_bf16(af[i], bfr[j], acc[i][j], 0, 0, 0);
    }

    // C/D layout: col = lane&15, row = quad*4 + reg
    u16* Cd = (u16*)C0;
    if (QKV) {
        int sel = bn >> 2;
        Cd = (sel == 0) ? (u16*)C0 : (sel == 1) ? (u16*)C1 : (u16*)C2;
    }
#pragma unroll
    for (int i = 0; i < 4; i++) {
        int row0 = bm * 128 + wm + i * 16 + quad * 4;
#pragma unroll
        for (int j = 0; j < 4; j++) {
            int colg = bn * 128 + wn + j * 16 + l15;   // global N index (bias)
            int col = QKV ? (colg & 511) : colg;
            float bv = bias[colg];
#pragma unroll
            for (int rr = 0; rr < 4; rr++) {
                int row = row0 + rr;
                float v = acc[i][j][rr] + bv;
                if (EPI == 1) {   // tanh-form GELU: |err| < 1e-3, tolerance 0.115
                    float zz = 1.5957691216f * (v + 0.044715f * v * v * v);  // 2*0.7978845608
                    float t = 1.0f - 2.0f / (__expf(zz) + 1.0f);             // tanh
                    v = 0.5f * v * (1.0f + t);
                }
                if (EPI == 2) v += b2f(res[(size_t)row * 512 + col]);
                if (OF32) ((float*)Cd)[(size_t)row * N + col] = v;
                else      ((u16*)Cd)[(size_t)row * N + col] = f2b(v);
            }
        }
    }
}

// ---------------- bias precompute: biasM[wtype][head][q][kpad=112] = rel_bias + mask, -1e30 pad ----------------
__global__ __launch_bounds__(256) void biasprep_k(const float* __restrict__ table, u16* __restrict__ biasM) {
    int idx = blockIdx.x * 256 + threadIdx.x;
    int k = idx % 112;
    int t = idx / 112;
    int q = t % 100; t /= 100;
    int head = t & 15, wt = t >> 4;
    float v;
    if (k >= 100) {
        v = -1e30f;
    } else {
        int qi = q / 10, qj = q - qi * 10;
        int ki = k / 10, kj = k - ki * 10;
        int rel = (qi - ki) * 19 + (qj - kj) + 180;   // = qoff - koff + 180
        v = table[rel * 16 + head];
        int rq = ((wt & 2) ? (qi < 5 ? 4 : 8) : 0) + ((wt & 1) ? (qj < 5 ? 1 : 2) : 0);
        int rk = ((wt & 2) ? (ki < 5 ? 4 : 8) : 0) + ((wt & 1) ? (kj < 5 ? 1 : 2) : 0);
        if (rq != rk) v -= 100.0f;
    }
    biasM[idx] = f2b(v);
}

// ---------------- MFMA windowed attention: one WAVE per (window, head) ----------------
// Swapped orientation: S^T[k][q] = K·(s·Q)^T + biasM  (scale folded into wq/bq upstream).
__global__ __launch_bounds__(256, 3) void attn_mfma_k(const u16* __restrict__ Q, const u16* __restrict__ Km,
                                                      const u16* __restrict__ V, const u16* __restrict__ biasM,
                                                      u16* __restrict__ ctx) {
    __shared__ __align__(16) u16 lds[4 * 6144];   // 48KB: 4 waves x (Vt 4096 + P 2048) u16
    int tid = threadIdx.x;
    int wave = tid >> 6, lane = tid & 63;
    int l15 = lane & 15, quad = lane >> 4;
    int bid = blockIdx.x;                 // 1536 blocks = 384 windows x 4
    int win = bid >> 2;
    int head = ((bid & 3) << 2) + wave;   // 4 waves cover 4 heads
    int w48 = win % 48;
    int wh = w48 / 6, ww = w48 - wh * 6;
    int wtype = ((wh == 7) ? 2 : 0) + ((ww == 5) ? 1 : 0);
    size_t base = (size_t)win * 51200 + head * 32;
    u16* Vt = lds + wave * 6144;          // [32 d][128 k] swizzled
    u16* Pl = Vt + 4096;                  // [16 q][128 k] swizzled
    const u16* bptr = biasM + (size_t)(wtype * 16 + head) * 11200;

    // zero Vt logical k in [96,128)
    {
        uint4 z = {0u, 0u, 0u, 0u};
#pragma unroll
        for (int r = 0; r < 2; r++) {
            int c = r * 64 + lane;
            int d = c >> 2, seg = c & 3;
            int k0 = 96 + seg * 8;
            *(uint4*)(Vt + d * 128 + (k0 ^ ((d & 7) << 3))) = z;
        }
        uint2 z2 = {0u, 0u};              // zero P logical k in [112,128)
        *(uint2*)(Pl + l15 * 128 + ((112 + quad * 4) ^ ((l15 & 7) << 3))) = z2;
    }
    // stage V transposed: Vt[d][k] = V[k][d]
#pragma unroll
    for (int r = 0; r < 2; r++) {
        int k = r * 64 + lane;
        if (k < 100) {
            const uint4* vp = (const uint4*)(V + base + (size_t)k * 512);
#pragma unroll
            for (int c = 0; c < 4; c++) {
                uint4 dv = vp[c];
                const u16* e = (const u16*)&dv;
#pragma unroll
                for (int t = 0; t < 8; t++) {
                    int d = c * 8 + t;
                    Vt[d * 128 + (k ^ ((d & 7) << 3))] = e[t];
                }
            }
        }
    }
    // K A-frags (resident)
    bf16x8 kf[7];
#pragma unroll
    for (int i = 0; i < 7; i++) {
        int kr = i * 16 + l15; if (kr > 99) kr = 99;
        kf[i] = *(const bf16x8*)(Km + base + (size_t)kr * 512 + quad * 8);
    }
    // V^T A-frags (resident)
    bf16x8 vf[2][4];
#pragma unroll
    for (int it = 0; it < 2; it++)
#pragma unroll
        for (int ks = 0; ks < 4; ks++) {
            int D = it * 16 + l15;
            vf[it][ks] = *(const bf16x8*)(Vt + D * 128 + ((ks * 32 + quad * 8) ^ ((D & 7) << 3)));
        }

#pragma unroll 1
    for (int j = 0; j < 7; j++) {
        int q = j * 16 + l15;
        int qc = q > 99 ? 99 : q;
        bf16x8 qf = *(const bf16x8*)(Q + base + (size_t)qc * 512 + quad * 8);
        f32x4 s[7];
#pragma unroll
        for (int i = 0; i < 7; i++) {
            uint2 bb = *(const uint2*)(bptr + (size_t)qc * 112 + i * 16 + quad * 4);
            const u16* be = (const u16*)&bb;
            s[i][0] = b2f(be[0]); s[i][1] = b2f(be[1]);
            s[i][2] = b2f(be[2]); s[i][3] = b2f(be[3]);
        }
#pragma unroll
        for (int i = 0; i < 7; i++)
            s[i] = __builtin_amdgcn_mfma_f32_16x16x32_bf16(kf[i], qf, s[i], 0, 0, 0);
        float m = -1e30f;
#pragma unroll
        for (int i = 0; i < 7; i++)
#pragma unroll
            for (int rr = 0; rr < 4; rr++) m = fmaxf(m, s[i][rr]);
        m = fmaxf(m, __shfl_xor(m, 16));
        m = fmaxf(m, __shfl_xor(m, 32));
        float l = 0.f;
#pragma unroll
        for (int i = 0; i < 7; i++)
#pragma unroll
            for (int rr = 0; rr < 4; rr++) { s[i][rr] = __expf(s[i][rr] - m); l += s[i][rr]; }
        l += __shfl_xor(l, 16);
        l += __shfl_xor(l, 32);
#pragma unroll
        for (int i = 0; i < 7; i++) {
            u32 lo, hi;
            asm("v_cvt_pk_bf16_f32 %0, %1, %2" : "=v"(lo) : "v"(s[i][0]), "v"(s[i][1]));
            asm("v_cvt_pk_bf16_f32 %0, %1, %2" : "=v"(hi) : "v"(s[i][2]), "v"(s[i][3]));
            uint2 w; w.x = lo; w.y = hi;
            *(uint2*)(Pl + l15 * 128 + ((i * 16 + quad * 4) ^ ((l15 & 7) << 3))) = w;
        }
        f32x4 o0 = (f32x4){0.f, 0.f, 0.f, 0.f};
        f32x4 o1 = (f32x4){0.f, 0.f, 0.f, 0.f};
#pragma unroll
        for (int ks = 0; ks < 4; ks++) {
            bf16x8 pf = *(const bf16x8*)(Pl + l15 * 128 + ((ks * 32 + quad * 8) ^ ((l15 & 7) << 3)));
            o0 = __builtin_amdgcn_mfma_f32_16x16x32_bf16(vf[0][ks], pf, o0, 0, 0, 0);
            o1 = __builtin_amdgcn_mfma_f32_16x16x32_bf16(vf[1][ks], pf, o1, 0, 0, 0);
        }
        float inv = 1.0f / l;
        if (q < 100) {
            u16* cp = ctx + base + (size_t)q * 512;
            {
                float a0 = o0[0]*inv, a1 = o0[1]*inv, a2 = o0[2]*inv, a3 = o0[3]*inv;
                u32 lo, hi;
                asm("v_cvt_pk_bf16_f32 %0, %1, %2" : "=v"(lo) : "v"(a0), "v"(a1));
                asm("v_cvt_pk_bf16_f32 %0, %1, %2" : "=v"(hi) : "v"(a2), "v"(a3));
                uint2 w; w.x = lo; w.y = hi;
                *(uint2*)(cp + quad * 4) = w;
            }
            {
                float a0 = o1[0]*inv, a1 = o1[1]*inv, a2 = o1[2]*inv, a3 = o1[3]*inv;
                u32 lo, hi;
                asm("v_cvt_pk_bf16_f32 %0, %1, %2" : "=v"(lo) : "v"(a0), "v"(a1));
                asm("v_cvt_pk_bf16_f32 %0, %1, %2" : "=v"(hi) : "v"(a2), "v"(a3));
                uint2 w; w.x = lo; w.y = hi;
                *(uint2*)(cp + 16 + quad * 4) = w;
            }
        }
    }
}

extern "C" void kernel_launch(void* const* d_in, const int* in_sizes, int n_in,
                              void* d_out, int out_size, void* d_ws, size_t ws_size,
                              hipStream_t stream) {
    const float* hidden = (const float*)d_in[0];
    const float* ln1_g  = (const float*)d_in[1];
    const float* ln1_b  = (const float*)d_in[2];
    const float* wq = (const float*)d_in[3];  const float* bq = (const float*)d_in[4];
    const float* wk = (const float*)d_in[5];  const float* bk = (const float*)d_in[6];
    const float* wv = (const float*)d_in[7];  const float* bv = (const float*)d_in[8];
    const float* wo = (const float*)d_in[9];  const float* bo = (const float*)d_in[10];
    const float* rel = (const float*)d_in[11];
    const float* ln2_g = (const float*)d_in[12];
    const float* ln2_b = (const float*)d_in[13];
    const float* w1 = (const float*)d_in[14]; const float* b1 = (const float*)d_in[15];
    const float* w2 = (const float*)d_in[16]; const float* b2 = (const float*)d_in[17];

    // ws: R0,R1,Rh = 3*NTC bf16 (118MB) + weights (+6KB qkv bias). d_out doubles as V / ln2y park.
    //   R0: win -> ctx -> h1 chunk ; R1: q -> attn_out ; Rh: k -> hs
    //   d_out lo (bf16): v -> ln2y ; biasM parked at d_out+NTC u16 (clobbered only by FFN mc=1 fp32 out).
    const size_t NTC = 38400ull * 512;
    u16* ws = (u16*)d_ws;
    u16* R0 = ws;
    u16* R1 = ws + NTC;
    u16* Rh = ws + 2 * NTC;
    u16* wqt = ws + 3 * NTC;
    u16* wkt = wqt + 512 * 512;
    u16* wvt = wkt + 512 * 512;       // wqt..wvt contiguous => fused QKV Bt (1536 x 512)
    u16* wot = wvt + 512 * 512;
    u16* w1t = wot + 512 * 512;       // (2048,512)
    u16* w2t = w1t + 1048576;         // (512,2048)
    float* qkvb = (float*)(w2t + 1048576);   // concat bias [1536]
    u16* dlo = (u16*)d_out;           // v, then ln2y (bf16)
    u16* biasM = dlo + NTC;           // [4][16][100][112] bf16
    float* outp = (float*)d_out;

    const float SC = 0.17677669529663689f;   // 1/sqrt(32), folded into wq/bq

    transpose_k<<<dim3(16, 16), 256, 0, stream>>>(wq, wqt, 512, 512, SC);
    transpose_k<<<dim3(16, 16), 256, 0, stream>>>(wk, wkt, 512, 512, 1.0f);
    transpose_k<<<dim3(16, 16), 256, 0, stream>>>(wv, wvt, 512, 512, 1.0f);
    transpose_k<<<dim3(16, 16), 256, 0, stream>>>(wo, wot, 512, 512, 1.0f);
    transpose_k<<<dim3(16, 64), 256, 0, stream>>>(w1, w1t, 512, 2048, 1.0f);
    transpose_k<<<dim3(64, 16), 256, 0, stream>>>(w2, w2t, 2048, 512, 1.0f);
    biascat_k<<<6, 256, 0, stream>>>(bq, bk, bv, qkvb);
    biasprep_k<<<2800, 256, 0, stream>>>(rel, biasM);   // 716800 = 2800*256

    ln1win_k<<<9600, 256, 0, stream>>>(hidden, ln1_g, ln1_b, R0 /*win*/);

    // fused QKV: N=1536 over contiguous wqt|wkt|wvt, outputs routed to R1 / Rh / dlo
    gemm_k<0, 0, 1><<<dim3(300, 12), 256, 0, stream>>>(R0, wqt, qkvb, nullptr,
                                                       R1 /*q*/, Rh /*k*/, dlo /*v*/, 38400, 512, 512);

    attn_mfma_k<<<1536, 256, 0, stream>>>(R1, Rh, dlo, biasM, R0 /*ctx*/);

    gemm_k<0, 0, 0><<<dim3(300, 4), 256, 0, stream>>>(R0, wot, bo, nullptr,
                                                      R1 /*attn_out*/, nullptr, nullptr, 38400, 512, 512);

    resid2_k<<<9600, 256, 0, stream>>>(hidden, R1, ln2_g, ln2_b, Rh /*hs*/, dlo /*ln2y*/);

    // FFN in 2 chunks of 19200 rows, REVERSE order so fp32 out writes never clobber unread bf16 ln2y:
    // chunk mc reads bf16 [mc*19.66MB, +19.66MB); writes fp32 [mc*39.32MB, +39.32MB).
    for (int mc = 1; mc >= 0; mc--) {
        size_t roff = (size_t)mc * 19200 * 512;
        gemm_k<1, 0, 0><<<dim3(150, 16), 256, 0, stream>>>(dlo + roff, w1t, b1, nullptr,
                                                           R0 /*h1*/, nullptr, nullptr, 19200, 2048, 512);
        gemm_k<2, 1, 0><<<dim3(150, 4), 256, 0, stream>>>(R0, w2t, b2, Rh + roff,
                                                          outp + roff, nullptr, nullptr, 19200, 512, 2048);
    }
}

// Round 4
// 724.855 us; speedup vs baseline: 1.4011x; 1.0345x over previous
//
#include <hip/hip_runtime.h>
#include <math.h>

typedef unsigned short u16;
typedef unsigned int u32;
typedef __bf16 bf16x8 __attribute__((ext_vector_type(8)));
typedef float f32x4 __attribute__((ext_vector_type(4)));

__device__ __forceinline__ float b2f(u16 u) { return __uint_as_float(((u32)u) << 16); }
__device__ __forceinline__ u16 f2b(float f) {
    u32 x = __float_as_uint(f);
    return (u16)((x + 0x7FFFu + ((x >> 16) & 1u)) >> 16);
}
__device__ __forceinline__ void load8f(const float* p, size_t idx, float* o) {
    const float4* q = (const float4*)(p + idx);
    float4 a = q[0], b = q[1];
    o[0]=a.x; o[1]=a.y; o[2]=a.z; o[3]=a.w; o[4]=b.x; o[5]=b.y; o[6]=b.z; o[7]=b.w;
}
// async global->LDS, 16B per lane; LDS dest = wave-uniform base + lane*16
__device__ __forceinline__ void gld16(const void* g, void* l) {
    __builtin_amdgcn_global_load_lds(
        (const __attribute__((address_space(1))) u32*)g,
        (__attribute__((address_space(3))) u32*)l, 16, 0, 0);
}

// ---------------- weight transpose+convert: Wt[n][k] = bf16(W[k][n] * scale) ----------------
__global__ __launch_bounds__(256) void transpose_k(const float* __restrict__ Win, u16* __restrict__ Wt,
                                                   int Kd, int Nd, float scale) {
    __shared__ u16 tile[32][33];
    int tx = threadIdx.x & 31, ty = threadIdx.x >> 5;
    int k0 = blockIdx.x << 5, n0 = blockIdx.y << 5;
#pragma unroll
    for (int r = 0; r < 4; r++)
        tile[ty + 8 * r][tx] = f2b(Win[(size_t)(k0 + ty + 8 * r) * Nd + (n0 + tx)] * scale);
    __syncthreads();
#pragma unroll
    for (int r = 0; r < 4; r++)
        Wt[(size_t)(n0 + ty + 8 * r) * Kd + (k0 + tx)] = tile[tx][ty + 8 * r];
}

// ---------------- concat qkv bias (scale folded into q part) ----------------
__global__ __launch_bounds__(256) void biascat_k(const float* __restrict__ bq, const float* __restrict__ bk,
                                                 const float* __restrict__ bv, float* __restrict__ o) {
    int i = blockIdx.x * 256 + threadIdx.x;   // 1536
    float v = (i < 512) ? bq[i] * 0.17677669529663689f : (i < 1024 ? bk[i - 512] : bv[i - 1024]);
    o[i] = v;
}

// ---------------- LN1 (stats fused) + shift + window partition ----------------
__global__ __launch_bounds__(256) void ln1win_k(const float* __restrict__ x, const float* __restrict__ g,
                                                const float* __restrict__ bta, u16* __restrict__ win) {
    int wave = threadIdx.x >> 6, lane = threadIdx.x & 63;
    int token = blockIdx.x * 4 + wave;                  // token-order row
    int b = token / 4800, rem = token - b * 4800;
    int h = rem / 60, w = rem - h * 60;
    int hr = h + 75; if (hr >= 80) hr -= 80;            // (h-5) mod 80 : rolled coord
    int wr = w + 55; if (wr >= 60) wr -= 60;
    int widx = (hr / 10) * 6 + (wr / 10);
    int l = (hr - (hr / 10) * 10) * 10 + (wr - (wr / 10) * 10);
    size_t dstrow = ((size_t)b * 48 + widx) * 100 + l;  // window-order row
    int c0 = lane * 8;
    float v[8]; load8f(x, (size_t)token * 512 + c0, v);
    float s = 0.f, s2 = 0.f;
#pragma unroll
    for (int e = 0; e < 8; e++) { s += v[e]; s2 += v[e] * v[e]; }
#pragma unroll
    for (int o = 32; o > 0; o >>= 1) { s += __shfl_xor(s, o); s2 += __shfl_xor(s2, o); }
    float mean = s * (1.0f / 512.0f);
    float var = fmaxf(s2 * (1.0f / 512.0f) - mean * mean, 0.0f);
    float rstd = rsqrtf(var + 1e-5f);
    uint4 o4; u16* ou = (u16*)&o4;
#pragma unroll
    for (int e = 0; e < 8; e++)
        ou[e] = f2b((v[e] - mean) * rstd * g[c0 + e] + bta[c0 + e]);
    *(uint4*)(win + dstrow * 512 + c0) = o4;
}

// ---------------- window reverse + residual + fused LN2: hs, ln2y ----------------
__global__ __launch_bounds__(256) void resid2_k(const float* __restrict__ shortcut, const u16* __restrict__ attn_out,
                                                const float* __restrict__ g, const float* __restrict__ bta,
                                                u16* __restrict__ hs, u16* __restrict__ ln2y) {
    int wave = threadIdx.x >> 6, lane = threadIdx.x & 63;
    int token = blockIdx.x * 4 + wave;
    int b = token / 4800, rem = token - b * 4800;
    int h = rem / 60, w = rem - h * 60;
    int hr = h + 75; if (hr >= 80) hr -= 80;
    int wr = w + 55; if (wr >= 60) wr -= 60;
    int widx = (hr / 10) * 6 + (wr / 10);
    int l = (hr - (hr / 10) * 10) * 10 + (wr - (wr / 10) * 10);
    size_t arow = ((size_t)b * 48 + widx) * 100 + l;
    int c0 = lane * 8;
    float sv[8]; load8f(shortcut, (size_t)token * 512 + c0, sv);
    uint4 da = *(const uint4*)(attn_out + arow * 512 + c0);
    const u16* au = (const u16*)&da;
    float hv[8]; float s = 0.f, s2 = 0.f;
    uint4 oh; u16* ohu = (u16*)&oh;
#pragma unroll
    for (int e = 0; e < 8; e++) {
        hv[e] = sv[e] + b2f(au[e]);
        s += hv[e]; s2 += hv[e] * hv[e];
        ohu[e] = f2b(hv[e]);
    }
    *(uint4*)(hs + (size_t)token * 512 + c0) = oh;
#pragma unroll
    for (int off = 32; off > 0; off >>= 1) { s += __shfl_xor(s, off); s2 += __shfl_xor(s2, off); }
    float mean = s * (1.0f / 512.0f);
    float var = fmaxf(s2 * (1.0f / 512.0f) - mean * mean, 0.0f);
    float rstd = rsqrtf(var + 1e-5f);
    uint4 oy; u16* oyu = (u16*)&oy;
#pragma unroll
    for (int e = 0; e < 8; e++)
        oyu[e] = f2b((hv[e] - mean) * rstd * g[c0 + e] + bta[c0 + e]);
    *(uint4*)(ln2y + (size_t)token * 512 + c0) = oy;
}

// ---------------- MFMA GEMM, depth-2 counted-vmcnt pipeline ----------------
// C = epi(A[M,K] @ Bt[N,K]^T + bias)
// EPI: 0 = bias; 1 = bias + tanh-GELU; 2 = bias + residual add (res bf16 [M,512])
// OF32: output fp32. QKV: N=512 stride, route output by bn>>2 to C0/C1/C2, bias indexed 0..1535.
// 3 LDS buffers (48KB), prefetch distance 2, s_waitcnt vmcnt(8) steady state (never 0 mid-loop).
template <int EPI, int OF32, int QKV>
__global__ __launch_bounds__(256) void gemm_k(const u16* __restrict__ A, const u16* __restrict__ Bt,
                                              const float* __restrict__ bias, const u16* __restrict__ res,
                                              void* __restrict__ C0, void* __restrict__ C1, void* __restrict__ C2,
                                              int M, int N, int K) {
    __shared__ __align__(16) u16 As[3][128 * 32];   // unpadded: required by global_load_lds lane mapping
    __shared__ __align__(16) u16 Bs[3][128 * 32];
    int tid = threadIdx.x;
    int wave = tid >> 6, lane = tid & 63;
    int l15 = lane & 15, quad = lane >> 4;
    int lq = lane >> 2, lr = lane & 3;           // 16 rows x 4 16B-chunks per wave round
    int wm = (wave >> 1) * 64, wn = (wave & 1) * 64;

    // XCD-aware chunked swizzle from the TRUE hw dispatch id (x-fastest linear order; HW
    // round-robins that id across the 8 XCDs). Each XCD gets a contiguous chunk of tiles,
    // bn-fastest, so one XCD covers all bn of a narrow bm range: A-panel (131KB/bm) fetched
    // once per XCD L2, B (<=2MB) L2-resident. (r2 bug: orig=bx*gy+by scattered same-bm tiles
    // across XCDs -> FETCH was 6x ideal.)
    int gy = gridDim.y;
    int nwg = gridDim.x * gy;
    int lid = blockIdx.x + blockIdx.y * gridDim.x;   // hw dispatch linear order
    int xcd = lid & 7, loc = lid >> 3;
    int q8 = nwg >> 3, r8 = nwg & 7;
    int wg = (xcd < r8 ? xcd * (q8 + 1) : r8 * (q8 + 1) + (xcd - r8) * q8) + loc;
    int bn = wg % gy, bm = wg / gy;

    f32x4 acc[4][4];
#pragma unroll
    for (int i = 0; i < 4; i++)
#pragma unroll
        for (int j = 0; j < 4; j++) acc[i][j] = (f32x4){0.f, 0.f, 0.f, 0.f};

    const u16* Ab = A + (size_t)(bm * 128) * K;
    const u16* Bb = Bt + (size_t)(bn * 128) * K;

    int T = K >> 5;   // K-steps of 32; K >= 64 always
    auto STAGE = [&](int b, int t) {
        int kt = t << 5;
#pragma unroll
        for (int h = 0; h < 2; h++) {
            int r = h * 64 + wave * 16 + lq;
            gld16(Ab + (size_t)r * K + kt + lr * 8, &As[b][(h * 64 + wave * 16) * 32]);
            gld16(Bb + (size_t)r * K + kt + lr * 8, &Bs[b][(h * 64 + wave * 16) * 32]);
        }
    };

    STAGE(0, 0);
    STAGE(1, 1);
    for (int t = 0; t < T; t++) {
        int cb = t % 3;
        if (t + 2 < T) STAGE((t + 2) % 3, t + 2);
        // wait for tile t only; keep tiles t+1 (and t+2) in flight across the barrier
        if (t + 2 < T)      asm volatile("s_waitcnt vmcnt(8)" ::: "memory");
        else if (t + 1 < T) asm volatile("s_waitcnt vmcnt(4)" ::: "memory");
        else                asm volatile("s_waitcnt vmcnt(0)" ::: "memory");
        __builtin_amdgcn_s_barrier();            // all waves: tile t resident in LDS
        asm volatile("" ::: "memory");
        bf16x8 af[4], bfr[4];
#pragma unroll
        for (int x = 0; x < 4; x++) {
            af[x]  = *(const bf16x8*)(&As[cb][(wm + x * 16 + l15) * 32 + quad * 8]);
            bfr[x] = *(const bf16x8*)(&Bs[cb][(wn + x * 16 + l15) * 32 + quad * 8]);
        }
        asm volatile("s_waitcnt lgkmcnt(0)" ::: "memory");
        __builtin_amdgcn_sched_barrier(0);       // rule #18: pin MFMA after lgkmcnt
        __builtin_amdgcn_s_barrier();            // all waves done reading buf[cb] (next iter overwrites it)
        asm volatile("" ::: "memory");
#pragma unroll
        for (int i = 0; i < 4; i++)
#pragma unroll
            for (int j = 0; j < 4; j++)
                acc[i][j] = __builtin_amdgcn_mfma_f32_16x16x32_bf16(af[i], bfr[j], acc[i][j], 0, 0, 0);
    }

    // C/D layout: col = lane&15, row = quad*4 + reg
    u16* Cd = (u16*)C0;
    if (QKV) {
        int sel = bn >> 2;
        Cd = (sel == 0) ? (u16*)C0 : (sel == 1) ? (u16*)C1 : (u16*)C2;
    }
#pragma unroll
    for (int i = 0; i < 4; i++) {
        int row0 = bm * 128 + wm + i * 16 + quad * 4;
#pragma unroll
        for (int j = 0; j < 4; j++) {
            int colg = bn * 128 + wn + j * 16 + l15;   // global N index (bias)
            int col = QKV ? (colg & 511) : colg;
            float bv = bias[colg];
#pragma unroll
            for (int rr = 0; rr < 4; rr++) {
                int row = row0 + rr;
                float v = acc[i][j][rr] + bv;
                if (EPI == 1) {   // tanh-form GELU: |err| < 1e-3, tolerance 0.115
                    float zz = 1.5957691216f * (v + 0.044715f * v * v * v);  // 2*0.7978845608
                    float t = 1.0f - 2.0f / (__expf(zz) + 1.0f);             // tanh
                    v = 0.5f * v * (1.0f + t);
                }
                if (EPI == 2) v += b2f(res[(size_t)row * 512 + col]);
                if (OF32) ((float*)Cd)[(size_t)row * N + col] = v;
                else      ((u16*)Cd)[(size_t)row * N + col] = f2b(v);
            }
        }
    }
}

// ---------------- bias precompute: biasM[wtype][head][q][kpad=112] = rel_bias + mask, -1e30 pad ----------------
__global__ __launch_bounds__(256) void biasprep_k(const float* __restrict__ table, u16* __restrict__ biasM) {
    int idx = blockIdx.x * 256 + threadIdx.x;
    int k = idx % 112;
    int t = idx / 112;
    int q = t % 100; t /= 100;
    int head = t & 15, wt = t >> 4;
    float v;
    if (k >= 100) {
        v = -1e30f;
    } else {
        int qi = q / 10, qj = q - qi * 10;
        int ki = k / 10, kj = k - ki * 10;
        int rel = (qi - ki) * 19 + (qj - kj) + 180;   // = qoff - koff + 180
        v = table[rel * 16 + head];
        int rq = ((wt & 2) ? (qi < 5 ? 4 : 8) : 0) + ((wt & 1) ? (qj < 5 ? 1 : 2) : 0);
        int rk = ((wt & 2) ? (ki < 5 ? 4 : 8) : 0) + ((wt & 1) ? (kj < 5 ? 1 : 2) : 0);
        if (rq != rk) v -= 100.0f;
    }
    biasM[idx] = f2b(v);
}

// ---------------- MFMA windowed attention: one WAVE per (window, head) ----------------
// Swapped orientation: S^T[k][q] = K·(s·Q)^T + biasM  (scale folded into wq/bq upstream).
__global__ __launch_bounds__(256, 3) void attn_mfma_k(const u16* __restrict__ Q, const u16* __restrict__ Km,
                                                      const u16* __restrict__ V, const u16* __restrict__ biasM,
                                                      u16* __restrict__ ctx) {
    __shared__ __align__(16) u16 lds[4 * 6144];   // 48KB: 4 waves x (Vt 4096 + P 2048) u16
    int tid = threadIdx.x;
    int wave = tid >> 6, lane = tid & 63;
    int l15 = lane & 15, quad = lane >> 4;
    int bid = blockIdx.x;                 // 1536 blocks = 384 windows x 4
    int win = bid >> 2;
    int head = ((bid & 3) << 2) + wave;   // 4 waves cover 4 heads
    int w48 = win % 48;
    int wh = w48 / 6, ww = w48 - wh * 6;
    int wtype = ((wh == 7) ? 2 : 0) + ((ww == 5) ? 1 : 0);
    size_t base = (size_t)win * 51200 + head * 32;
    u16* Vt = lds + wave * 6144;          // [32 d][128 k] swizzled
    u16* Pl = Vt + 4096;                  // [16 q][128 k] swizzled
    const u16* bptr = biasM + (size_t)(wtype * 16 + head) * 11200;

    // zero Vt logical k in [96,128)
    {
        uint4 z = {0u, 0u, 0u, 0u};
#pragma unroll
        for (int r = 0; r < 2; r++) {
            int c = r * 64 + lane;
            int d = c >> 2, seg = c & 3;
            int k0 = 96 + seg * 8;
            *(uint4*)(Vt + d * 128 + (k0 ^ ((d & 7) << 3))) = z;
        }
        uint2 z2 = {0u, 0u};              // zero P logical k in [112,128)
        *(uint2*)(Pl + l15 * 128 + ((112 + quad * 4) ^ ((l15 & 7) << 3))) = z2;
    }
    // stage V transposed: Vt[d][k] = V[k][d]
#pragma unroll
    for (int r = 0; r < 2; r++) {
        int k = r * 64 + lane;
        if (k < 100) {
            const uint4* vp = (const uint4*)(V + base + (size_t)k * 512);
#pragma unroll
            for (int c = 0; c < 4; c++) {
                uint4 dv = vp[c];
                const u16* e = (const u16*)&dv;
#pragma unroll
                for (int t = 0; t < 8; t++) {
                    int d = c * 8 + t;
                    Vt[d * 128 + (k ^ ((d & 7) << 3))] = e[t];
                }
            }
        }
    }
    // K A-frags (resident)
    bf16x8 kf[7];
#pragma unroll
    for (int i = 0; i < 7; i++) {
        int kr = i * 16 + l15; if (kr > 99) kr = 99;
        kf[i] = *(const bf16x8*)(Km + base + (size_t)kr * 512 + quad * 8);
    }
    // V^T A-frags (resident)
    bf16x8 vf[2][4];
#pragma unroll
    for (int it = 0; it < 2; it++)
#pragma unroll
        for (int ks = 0; ks < 4; ks++) {
            int D = it * 16 + l15;
            vf[it][ks] = *(const bf16x8*)(Vt + D * 128 + ((ks * 32 + quad * 8) ^ ((D & 7) << 3)));
        }

#pragma unroll 1
    for (int j = 0; j < 7; j++) {
        int q = j * 16 + l15;
        int qc = q > 99 ? 99 : q;
        bf16x8 qf = *(const bf16x8*)(Q + base + (size_t)qc * 512 + quad * 8);
        f32x4 s[7];
#pragma unroll
        for (int i = 0; i < 7; i++) {
            uint2 bb = *(const uint2*)(bptr + (size_t)qc * 112 + i * 16 + quad * 4);
            const u16* be = (const u16*)&bb;
            s[i][0] = b2f(be[0]); s[i][1] = b2f(be[1]);
            s[i][2] = b2f(be[2]); s[i][3] = b2f(be[3]);
        }
#pragma unroll
        for (int i = 0; i < 7; i++)
            s[i] = __builtin_amdgcn_mfma_f32_16x16x32_bf16(kf[i], qf, s[i], 0, 0, 0);
        float m = -1e30f;
#pragma unroll
        for (int i = 0; i < 7; i++)
#pragma unroll
            for (int rr = 0; rr < 4; rr++) m = fmaxf(m, s[i][rr]);
        m = fmaxf(m, __shfl_xor(m, 16));
        m = fmaxf(m, __shfl_xor(m, 32));
        float l = 0.f;
#pragma unroll
        for (int i = 0; i < 7; i++)
#pragma unroll
            for (int rr = 0; rr < 4; rr++) { s[i][rr] = __expf(s[i][rr] - m); l += s[i][rr]; }
        l += __shfl_xor(l, 16);
        l += __shfl_xor(l, 32);
#pragma unroll
        for (int i = 0; i < 7; i++) {
            u32 lo, hi;
            asm("v_cvt_pk_bf16_f32 %0, %1, %2" : "=v"(lo) : "v"(s[i][0]), "v"(s[i][1]));
            asm("v_cvt_pk_bf16_f32 %0, %1, %2" : "=v"(hi) : "v"(s[i][2]), "v"(s[i][3]));
            uint2 w; w.x = lo; w.y = hi;
            *(uint2*)(Pl + l15 * 128 + ((i * 16 + quad * 4) ^ ((l15 & 7) << 3))) = w;
        }
        f32x4 o0 = (f32x4){0.f, 0.f, 0.f, 0.f};
        f32x4 o1 = (f32x4){0.f, 0.f, 0.f, 0.f};
#pragma unroll
        for (int ks = 0; ks < 4; ks++) {
            bf16x8 pf = *(const bf16x8*)(Pl + l15 * 128 + ((ks * 32 + quad * 8) ^ ((l15 & 7) << 3)));
            o0 = __builtin_amdgcn_mfma_f32_16x16x32_bf16(vf[0][ks], pf, o0, 0, 0, 0);
            o1 = __builtin_amdgcn_mfma_f32_16x16x32_bf16(vf[1][ks], pf, o1, 0, 0, 0);
        }
        float inv = 1.0f / l;
        if (q < 100) {
            u16* cp = ctx + base + (size_t)q * 512;
            {
                float a0 = o0[0]*inv, a1 = o0[1]*inv, a2 = o0[2]*inv, a3 = o0[3]*inv;
                u32 lo, hi;
                asm("v_cvt_pk_bf16_f32 %0, %1, %2" : "=v"(lo) : "v"(a0), "v"(a1));
                asm("v_cvt_pk_bf16_f32 %0, %1, %2" : "=v"(hi) : "v"(a2), "v"(a3));
                uint2 w; w.x = lo; w.y = hi;
                *(uint2*)(cp + quad * 4) = w;
            }
            {
                float a0 = o1[0]*inv, a1 = o1[1]*inv, a2 = o1[2]*inv, a3 = o1[3]*inv;
                u32 lo, hi;
                asm("v_cvt_pk_bf16_f32 %0, %1, %2" : "=v"(lo) : "v"(a0), "v"(a1));
                asm("v_cvt_pk_bf16_f32 %0, %1, %2" : "=v"(hi) : "v"(a2), "v"(a3));
                uint2 w; w.x = lo; w.y = hi;
                *(uint2*)(cp + 16 + quad * 4) = w;
            }
        }
    }
}

extern "C" void kernel_launch(void* const* d_in, const int* in_sizes, int n_in,
                              void* d_out, int out_size, void* d_ws, size_t ws_size,
                              hipStream_t stream) {
    const float* hidden = (const float*)d_in[0];
    const float* ln1_g  = (const float*)d_in[1];
    const float* ln1_b  = (const float*)d_in[2];
    const float* wq = (const float*)d_in[3];  const float* bq = (const float*)d_in[4];
    const float* wk = (const float*)d_in[5];  const float* bk = (const float*)d_in[6];
    const float* wv = (const float*)d_in[7];  const float* bv = (const float*)d_in[8];
    const float* wo = (const float*)d_in[9];  const float* bo = (const float*)d_in[10];
    const float* rel = (const float*)d_in[11];
    const float* ln2_g = (const float*)d_in[12];
    const float* ln2_b = (const float*)d_in[13];
    const float* w1 = (const float*)d_in[14]; const float* b1 = (const float*)d_in[15];
    const float* w2 = (const float*)d_in[16]; const float* b2 = (const float*)d_in[17];

    // ws: R0,R1,Rh = 3*NTC bf16 (118MB) + weights (+6KB qkv bias). d_out doubles as V / ln2y park.
    //   R0: win -> ctx -> h1 chunk ; R1: q -> attn_out ; Rh: k -> hs
    //   d_out lo (bf16): v -> ln2y ; biasM parked at d_out+NTC u16 (clobbered only by FFN mc=1 fp32 out).
    const size_t NTC = 38400ull * 512;
    u16* ws = (u16*)d_ws;
    u16* R0 = ws;
    u16* R1 = ws + NTC;
    u16* Rh = ws + 2 * NTC;
    u16* wqt = ws + 3 * NTC;
    u16* wkt = wqt + 512 * 512;
    u16* wvt = wkt + 512 * 512;       // wqt..wvt contiguous => fused QKV Bt (1536 x 512)
    u16* wot = wvt + 512 * 512;
    u16* w1t = wot + 512 * 512;       // (2048,512)
    u16* w2t = w1t + 1048576;         // (512,2048)
    float* qkvb = (float*)(w2t + 1048576);   // concat bias [1536]
    u16* dlo = (u16*)d_out;           // v, then ln2y (bf16)
    u16* biasM = dlo + NTC;           // [4][16][100][112] bf16
    float* outp = (float*)d_out;

    const float SC = 0.17677669529663689f;   // 1/sqrt(32), folded into wq/bq

    transpose_k<<<dim3(16, 16), 256, 0, stream>>>(wq, wqt, 512, 512, SC);
    transpose_k<<<dim3(16, 16), 256, 0, stream>>>(wk, wkt, 512, 512, 1.0f);
    transpose_k<<<dim3(16, 16), 256, 0, stream>>>(wv, wvt, 512, 512, 1.0f);
    transpose_k<<<dim3(16, 16), 256, 0, stream>>>(wo, wot, 512, 512, 1.0f);
    transpose_k<<<dim3(16, 64), 256, 0, stream>>>(w1, w1t, 512, 2048, 1.0f);
    transpose_k<<<dim3(64, 16), 256, 0, stream>>>(w2, w2t, 2048, 512, 1.0f);
    biascat_k<<<6, 256, 0, stream>>>(bq, bk, bv, qkvb);
    biasprep_k<<<2800, 256, 0, stream>>>(rel, biasM);   // 716800 = 2800*256

    ln1win_k<<<9600, 256, 0, stream>>>(hidden, ln1_g, ln1_b, R0 /*win*/);

    // fused QKV: N=1536 over contiguous wqt|wkt|wvt, outputs routed to R1 / Rh / dlo
    gemm_k<0, 0, 1><<<dim3(300, 12), 256, 0, stream>>>(R0, wqt, qkvb, nullptr,
                                                       R1 /*q*/, Rh /*k*/, dlo /*v*/, 38400, 512, 512);

    attn_mfma_k<<<1536, 256, 0, stream>>>(R1, Rh, dlo, biasM, R0 /*ctx*/);

    gemm_k<0, 0, 0><<<dim3(300, 4), 256, 0, stream>>>(R0, wot, bo, nullptr,
                                                      R1 /*attn_out*/, nullptr, nullptr, 38400, 512, 512);

    resid2_k<<<9600, 256, 0, stream>>>(hidden, R1, ln2_g, ln2_b, Rh /*hs*/, dlo /*ln2y*/);

    // FFN in 2 chunks of 19200 rows, REVERSE order so fp32 out writes never clobber unread bf16 ln2y:
    // chunk mc reads bf16 [mc*19.66MB, +19.66MB); writes fp32 [mc*39.32MB, +39.32MB).
    for (int mc = 1; mc >= 0; mc--) {
        size_t roff = (size_t)mc * 19200 * 512;
        gemm_k<1, 0, 0><<<dim3(150, 16), 256, 0, stream>>>(dlo + roff, w1t, b1, nullptr,
                                                           R0 /*h1*/, nullptr, nullptr, 19200, 2048, 512);
        gemm_k<2, 1, 0><<<dim3(150, 4), 256, 0, stream>>>(R0, w2t, b2, Rh + roff,
                                                          outp + roff, nullptr, nullptr, 19200, 512, 2048);
    }
}